// Round 2
// baseline (629.239 us; speedup 1.0000x reference)
//
#include <hip/hip_runtime.h>

#define NT 32
#define EPSF 1e-8f

// ================= Gram kernel =================
// G = vecs @ vecs^T, vecs (32, D) fp32 row-major.
// Staging: lane l owns column (base+l); loads its 32 row values as scalar
// dwords (coalesced 256B/instr across lanes), writes 8x ds_write_b128 into a
// swizzled column-major LDS tile: addr(r, j) = j*32 + ((r>>2) ^ (j&7))*4 + (r&3).
// Writes hit all 8 bank phases (floor rate); compute reads are 2-way (free).
// Compute: lane (cj,pi,pk) accumulates the 8x8 patch rows 8pi.., cols 8pk..,
// with cj splitting tile columns 4-ways; no barrier/fence in K-loop
// (wave-private tile, per-wave DS ops are in-order).
#define TILE_COLS 64
#define GR_THREADS 256
#define WAVES_PB 4
#define TILES_PW 8    // cols/wave = 512, cols/block = 2048 -> grid = 1024 = 4 blk/CU

__global__ __launch_bounds__(GR_THREADS, 4)
void gram_kernel(const float* __restrict__ vecs, double* __restrict__ Gd, int D)
{
    __shared__ __align__(16) float tile[WAVES_PB][TILE_COLS * 32];
    __shared__ float Gpart[NT * NT];

    const int tid  = threadIdx.x;
    const int wave = tid >> 6;
    const int lane = tid & 63;

    for (int e = tid; e < NT * NT; e += GR_THREADS) Gpart[e] = 0.0f;
    __syncthreads();

    float* my = tile[wave];
    const int swz = lane & 7;

    const int cj = lane >> 4;        // column subgroup 0..3
    const int pi = (lane >> 2) & 3;  // patch rows 8*pi..
    const int pk = lane & 3;         // patch cols 8*pk..

    float acc[8][8];
#pragma unroll
    for (int r = 0; r < 8; r++)
#pragma unroll
        for (int c = 0; c < 8; c++) acc[r][c] = 0.0f;

    const long base0 = (long)blockIdx.x * (WAVES_PB * TILES_PW * TILE_COLS)
                     + (long)wave * (TILES_PW * TILE_COLS) + lane;

    float pre[32];
#pragma unroll
    for (int r = 0; r < 32; r++) pre[r] = vecs[(long)r * D + base0];

    for (int t = 0; t < TILES_PW; t++) {
        // stage tile t: 8 contiguous b128 writes per lane, swizzled chunks
#pragma unroll
        for (int rg = 0; rg < 8; rg++) {
            float4 w = make_float4(pre[4 * rg], pre[4 * rg + 1],
                                   pre[4 * rg + 2], pre[4 * rg + 3]);
            *(float4*)(my + lane * 32 + (((rg ^ swz)) << 2)) = w;
        }
        // prefetch tile t+1 (flies during compute below)
        if (t + 1 < TILES_PW) {
            const long b = base0 + (long)(t + 1) * TILE_COLS;
#pragma unroll
            for (int r = 0; r < 32; r++) pre[r] = vecs[(long)r * D + b];
        }
#pragma unroll
        for (int jt = 0; jt < 16; jt++) {
            const int j = (jt << 2) + cj;
            const float* col = my + j * 32;
            const int js = j & 7;
            const float4 a0 = *(const float4*)(col + (((2 * pi) ^ js) << 2));
            const float4 a1 = *(const float4*)(col + (((2 * pi + 1) ^ js) << 2));
            const float4 b0 = *(const float4*)(col + (((2 * pk) ^ js) << 2));
            const float4 b1 = *(const float4*)(col + (((2 * pk + 1) ^ js) << 2));
            const float a[8] = {a0.x, a0.y, a0.z, a0.w, a1.x, a1.y, a1.z, a1.w};
            const float b[8] = {b0.x, b0.y, b0.z, b0.w, b1.x, b1.y, b1.z, b1.w};
#pragma unroll
            for (int r = 0; r < 8; r++)
#pragma unroll
                for (int c = 0; c < 8; c++)
                    acc[r][c] = fmaf(a[r], b[c], acc[r][c]);
        }
    }

    // fold the cj column-split (lanes sharing lane&15 share a patch)
#pragma unroll
    for (int r = 0; r < 8; r++)
#pragma unroll
        for (int c = 0; c < 8; c++) {
            float v = acc[r][c];
            v += __shfl_xor(v, 16);
            v += __shfl_xor(v, 32);
            if (lane < 16)
                atomicAdd(&Gpart[(8 * pi + r) * NT + (8 * pk + c)], v);
        }
    __syncthreads();
    for (int e = tid; e < NT * NT; e += GR_THREADS)
        atomicAdd(&Gd[e], (double)Gpart[e]);
}

// ================= Solver kernel =================
// DPP helpers (VALU-speed cross-lane; DS shuffles only where xor4/8/16 needed)
template<int CTRL>
__device__ __forceinline__ float dpp0(float x) {  // invalid source lanes -> 0
    return __int_as_float(__builtin_amdgcn_update_dpp(
        0, __float_as_int(x), CTRL, 0xF, 0xF, true));
}
template<int CTRL>
__device__ __forceinline__ float dppk(float oldv, float x) {  // invalid -> oldv
    return __int_as_float(__builtin_amdgcn_update_dpp(
        __float_as_int(oldv), __float_as_int(x), CTRL, 0xF, 0xF, false));
}
__device__ __forceinline__ float rdlane(float x, int l) {
    return __int_as_float(__builtin_amdgcn_readlane(__float_as_int(x), l));
}

// sum over lanes 0..31, uniform result (same fp tree as xor-butterfly)
__device__ __forceinline__ float bsum32u(float v) {
    v += dpp0<0x111>(v);  // row_shr:1
    v += dpp0<0x112>(v);  // row_shr:2
    v += dpp0<0x114>(v);  // row_shr:4
    v += dpp0<0x118>(v);  // row_shr:8
    return rdlane(v, 15) + rdlane(v, 31);
}
__device__ __forceinline__ float bmin32u(float v) {
    v = fminf(v, dppk<0x111>(v, v));
    v = fminf(v, dppk<0x112>(v, v));
    v = fminf(v, dppk<0x114>(v, v));
    v = fminf(v, dppk<0x118>(v, v));
    return fminf(rdlane(v, 15), rdlane(v, 31));
}

template<int J>
__device__ __forceinline__ float partner(float x) {
    if constexpr (J == 1)
        return dpp0<0xB1>(x);   // quad_perm [1,0,3,2] = xor 1
    else if constexpr (J == 2)
        return dpp0<0x4E>(x);   // quad_perm [2,3,0,1] = xor 2
    else if constexpr (J == 4)
        return __int_as_float(__builtin_amdgcn_ds_swizzle(__float_as_int(x), 0x101F));
    else if constexpr (J == 8)
        return __int_as_float(__builtin_amdgcn_ds_swizzle(__float_as_int(x), 0x201F));
    else
        return __int_as_float(__builtin_amdgcn_ds_swizzle(__float_as_int(x), 0x401F));
}

__global__ __launch_bounds__(64)
void solver_kernel(const double* __restrict__ Gd, float* __restrict__ out)
{
    __shared__ float Gsh[NT * 33];
    const int lane = threadIdx.x;  // one wave

    for (int t2 = 0; t2 < 16; t2++) {
        int e = t2 * 64 + lane;
        Gsh[(e >> 5) * 33 + (e & 31)] = (float)Gd[e];
    }
    __syncthreads();

    float Grow[NT];
#pragma unroll
    for (int k = 0; k < NT; k++)
        Grow[k] = (lane < NT) ? Gsh[lane * 33 + k] : 0.0f;

    // ---- planar init: argmin over all 496 (a<b) pairs ----
    float bestCost = INFINITY, bestGamma = 0.0f;
    int bestEnc = 0x7FFFFFFF;
    for (int a = 0; a < NT - 1; a++) {
        int b = a + 1 + lane;
        if (b < NT) {
            float v11 = Gsh[a * 33 + a];
            float v12 = Gsh[a * 33 + b];
            float v22 = Gsh[b * 33 + b];
            float g = (v22 - v12) / (v11 + v22 - 2.0f * v12 + EPSF);
            float c = v22 + g * (v12 - v22);
            float gamma = (v12 >= v22) ? 0.0f : g;
            float cost  = (v12 >= v22) ? v22 : c;
            if (v12 >= v11) { gamma = 1.0f; cost = v11; }
            int enc = a * NT + b;
            if (cost < bestCost) { bestCost = cost; bestEnc = enc; bestGamma = gamma; }
        }
    }
#pragma unroll
    for (int m = 1; m < 64; m <<= 1) {
        float oc = __shfl_xor(bestCost, m);
        int   oe = __shfl_xor(bestEnc, m);
        float og = __shfl_xor(bestGamma, m);
        if (oc < bestCost || (oc == bestCost && oe < bestEnc)) {
            bestCost = oc; bestEnc = oe; bestGamma = og;
        }
    }
    const int bi = bestEnc >> 5, bj = bestEnc & 31;

    float sol = 0.0f;
    if (lane == bi) sol = bestGamma;
    if (lane == bj) sol = 1.0f - bestGamma;

    for (int it = 0; it < 250; it++) {
        // Gsol = G @ sol via readlane broadcasts (VALU, no DS)
        float s0 = 0, s1 = 0, s2 = 0, s3 = 0;
#pragma unroll
        for (int k = 0; k < NT; k += 4) {
            s0 = fmaf(Grow[k + 0], rdlane(sol, k + 0), s0);
            s1 = fmaf(Grow[k + 1], rdlane(sol, k + 1), s1);
            s2 = fmaf(Grow[k + 2], rdlane(sol, k + 2), s2);
            s3 = fmaf(Grow[k + 3], rdlane(sol, k + 3), s3);
        }
        float Gsol = (s0 + s1) + (s2 + s3);

        // ---- next_point ----
        float grad = -Gsol;
        float proj = grad - bsum32u(grad) * 0.03125f;

        float tm1 = (proj < 0.0f) ? (-sol / proj) : INFINITY;
        float tm2 = (proj > 0.0f) ? ((1.0f - sol) / proj) : INFINITY;
        float m1 = bmin32u((tm1 > 1e-7f) ? tm1 : INFINITY);
        float m2 = bmin32u((tm2 > 1e-7f) ? tm2 : INFINITY);
        float t = __builtin_isinf(m1) ? 1.0f : m1;
        t = fminf(t, m2);
        float nxt = fmaf(proj, t, sol);

        // ---- simplex projection: bitonic sort desc over lanes 0..31 ----
        float s = nxt;
#define BSTAGE(KK, JJ) { \
        float pp = partner<JJ>(s); \
        bool descSeg = (lane & KK) == 0; \
        bool lower = (lane & JJ) == 0; \
        float mn = fminf(s, pp), mx = fmaxf(s, pp); \
        s = (descSeg == lower) ? mx : mn; }
        BSTAGE(2, 1)
        BSTAGE(4, 2)  BSTAGE(4, 1)
        BSTAGE(8, 4)  BSTAGE(8, 2)  BSTAGE(8, 1)
        BSTAGE(16, 8) BSTAGE(16, 4) BSTAGE(16, 2) BSTAGE(16, 1)
        BSTAGE(32, 16) BSTAGE(32, 8) BSTAGE(32, 4) BSTAGE(32, 2) BSTAGE(32, 1)
#undef BSTAGE

        // inclusive prefix sum over lanes 0..31 (row-confined + bcast15 fixup)
        float cs = s;
        cs += dpp0<0x111>(cs);
        cs += dpp0<0x112>(cs);
        cs += dpp0<0x114>(cs);
        cs += dpp0<0x118>(cs);
        float bc = dppk<0x142>(0.0f, cs);     // lanes16-31 <- lane15
        cs += (lane & 16) ? bc : 0.0f;

        float tmpm = (cs - 1.0f) / (float)((lane & 31) + 1);
        // snext = s from lane+1 (row_shl:1; patch the 15->16 boundary)
        float snext = dppk<0x101>(s, s);
        float s16 = rdlane(s, 16);
        if ((lane & 31) == 15) snext = s16;
        bool cond = ((lane & 31) < 31) && (tmpm > snext);
        unsigned long long bal = __ballot(cond ? 1 : 0) & 0x7FFFFFFFull;
        float tmax;
        if (bal != 0ULL) {
            int first = __builtin_ctzll(bal);
            tmax = rdlane(tmpm, first);
        } else {
            tmax = rdlane(tmpm, 31);
        }
        float newp = fmaxf(nxt - tmax, 0.0f);
        if (lane >= NT) newp = 0.0f;

        // Gn = G @ newp
        float n0 = 0, n1 = 0, n2 = 0, n3 = 0;
#pragma unroll
        for (int k = 0; k < NT; k += 4) {
            n0 = fmaf(Grow[k + 0], rdlane(newp, k + 0), n0);
            n1 = fmaf(Grow[k + 1], rdlane(newp, k + 1), n1);
            n2 = fmaf(Grow[k + 2], rdlane(newp, k + 2), n2);
            n3 = fmaf(Grow[k + 3], rdlane(newp, k + 3), n3);
        }
        float Gn = (n0 + n1) + (n2 + n3);

        float v11 = bsum32u(sol * Gsol);
        float v12 = bsum32u(sol * Gn);
        float v22 = bsum32u(newp * Gn);

        float g = (v22 - v12) / (v11 + v22 - 2.0f * v12 + EPSF);
        float gamma = (v12 >= v22) ? 0.0f : g;
        gamma = (v12 >= v11) ? 1.0f : gamma;

        float new_sol = gamma * sol + (1.0f - gamma) * newp;
        float diff = bsum32u(fabsf(new_sol - sol));
        if (diff < 1e-6f) break;   // freeze: output the OLD sol (ref semantics)
        sol = new_sol;
    }
    if (lane < NT) out[lane] = sol;
}

extern "C" void kernel_launch(void* const* d_in, const int* in_sizes, int n_in,
                              void* d_out, int out_size, void* d_ws, size_t ws_size,
                              hipStream_t stream) {
    const float* vecs = (const float*)d_in[0];
    float* out = (float*)d_out;
    double* Gd = (double*)d_ws;          // 1024 doubles = 8 KB
    const int D = in_sizes[0] / NT;      // 2097152

    hipMemsetAsync(Gd, 0, NT * NT * sizeof(double), stream);

    const int cols_per_block = WAVES_PB * TILES_PW * TILE_COLS;  // 2048
    const int grid = D / cols_per_block;                          // 1024
    gram_kernel<<<grid, GR_THREADS, 0, stream>>>(vecs, Gd, D);
    solver_kernel<<<1, 64, 0, stream>>>(Gd, out);
}